// Round 8
// baseline (803.514 us; speedup 1.0000x reference)
//
#include <hip/hip_runtime.h>
#include <hip/hip_bf16.h>
#include <cstddef>

#define L_SEQ   4096
#define BATCH   32
#define TOFF    1024
#define TBUF    3072
#define NLAYERS 30

typedef __attribute__((ext_vector_type(8))) short short8v;
typedef __attribute__((ext_vector_type(4))) float f32x4;

static const size_t HSZ = (size_t)BATCH * TBUF * 64;

// ---- single-layer kernel LDS (65536 B) ----
#define L_A  0        // A 128x128k bf16 stride 256B swizzled; z overlays own rows
#define L_B  32768    // W1 128x128k bf16 stride 256B swizzled

// ---- group kernel LDS (65536 B) ----
#define G_H  0        // h bf16 [192][64ch] stride 128B, swizzled (24576 B)
#define G_B  24576    // W1 bf16 [128][128] stride 256B, swizzled (32768 B)
#define G_Z  57344    // z: 4 waves x 16 rows x 128B (8192 B); ztap overlays [0,256)

__device__ inline float fast_sigmoid(float x) {
  x = fminf(fmaxf(x, -30.f), 30.f);
  return __builtin_amdgcn_rcpf(1.f + __expf(-x));
}
__device__ inline float fast_tanh(float x) {
  x = fminf(fmaxf(x, -15.f), 15.f);
  float e = __expf(-2.f * x);
  return (1.f - e) * __builtin_amdgcn_rcpf(1.f + e);
}
__device__ inline unsigned short f2bf(float f) {  // RNE fp32 -> bf16
  unsigned u = __float_as_uint(f);
  unsigned r = u + 0x7FFF + ((u >> 16) & 1);
  return (unsigned short)(r >> 16);
}
__device__ inline float bf2f(unsigned short u) {
  return __uint_as_float((unsigned)u << 16);
}
__device__ inline short8v lds_frag(const char* smem, int base, int row, int kk,
                                   int rowstride) {
  int byte = base + row * rowstride + kk * 2;
  byte ^= (row & 7) << 4;
  return *(const short8v*)(smem + byte);
}

// ---------------------------------------------------------------------------
__global__ __launch_bounds__(256) void prep_kernel(
    const float* __restrict__ dil_w, const float* __restrict__ gate_w,
    const float* __restrict__ res_w,
    unsigned short* __restrict__ W1bf, unsigned short* __restrict__ Wrbf,
    float* __restrict__ skip_last)
{
  int idx = blockIdx.x * 256 + threadIdx.x;
  if (idx < NLAYERS * 128 * 128) {
    int l = idx >> 14, r = idx & 16383, n = r >> 7, k = r & 127;
    const float* src = (n < 64) ? dil_w : gate_w;
    int oc = n & 63;
    float v = src[(((size_t)l * 64 + oc) * 64 + (k & 63)) * 2 + (k >> 6)];
    W1bf[idx] = f2bf(v);
  }
  if (idx < NLAYERS * 64 * 64) Wrbf[idx] = f2bf(res_w[idx]);
  if (idx < BATCH * 64) skip_last[idx] = 0.f;
}

// ---------------------------------------------------------------------------
__global__ __launch_bounds__(256) void input_conv_kernel(
    const float* __restrict__ x, const float* __restrict__ w,
    const float* __restrict__ bias, float* __restrict__ h)
{
  int b = blockIdx.y;
  int t = 1027 + blockIdx.x * 256 + threadIdx.x;
  if (t >= L_SEQ) return;
  const float* xp = x + ((size_t)b * L_SEQ + t) * 32;
  float xin[32];
#pragma unroll
  for (int j = 0; j < 8; ++j) {
    float4 v = ((const float4*)xp)[j];
    xin[4*j+0] = v.x; xin[4*j+1] = v.y; xin[4*j+2] = v.z; xin[4*j+3] = v.w;
  }
  float* hp = h + ((size_t)b * TBUF + (t - TOFF)) * 64;
#pragma unroll
  for (int half = 0; half < 2; ++half) {
    float acc[32];
#pragma unroll 2
    for (int o = 0; o < 32; ++o) {
      int oc = half * 32 + o;
      float a0 = bias[oc], a1 = 0.f;
#pragma unroll
      for (int k = 0; k < 32; k += 2) {
        a0 += w[oc * 32 + k]     * xin[k];
        a1 += w[oc * 32 + k + 1] * xin[k + 1];
      }
      acc[o] = a0 + a1;
    }
#pragma unroll
    for (int q = 0; q < 8; ++q)
      ((float4*)hp)[half * 8 + q] =
          make_float4(acc[4*q+0], acc[4*q+1], acc[4*q+2], acc[4*q+3]);
  }
}

// ---------------------------------------------------------------------------
// GROUP kernel: 6 layers (d = 1,2,4,8,16,32; halo 63) fused.
// Block = 192 staged rows (owns top 128), 4 waves, 48 rows/wave (3 fragments).
// fp32 h lives in registers (hreg), bf16 h in LDS, rewritten per layer.
// Top block (blockIdx.x==0) also computes the t=L skip tap per layer (wave 0).
// ---------------------------------------------------------------------------
__global__ __launch_bounds__(256, 2) void group_kernel(
    const float* __restrict__ hin, float* __restrict__ hout,
    const unsigned short* __restrict__ W1bf, const unsigned short* __restrict__ Wrbf,
    const float* __restrict__ dil_w, const float* __restrict__ gate_w,
    const float* __restrict__ skip_w,
    const float* __restrict__ dil_b, const float* __restrict__ gate_b,
    const float* __restrict__ res_b, const float* __restrict__ skip_b,
    float* __restrict__ skip_last, int i0, int R_i0)
{
  extern __shared__ char smem[];
  float* ztap = (float*)(smem + G_Z);  // wave0-private overlay of z slots 0-1
  const int b   = blockIdx.y;
  const int tid = threadIdx.x;
  const int t0  = L_SEQ - 128 * (blockIdx.x + 1);
  const int ts  = t0 - 64;                 // staged base (192 rows)
  const bool top = (blockIdx.x == 0);
  const int lane = tid & 63, wv = tid >> 6;
  const int lcol = lane & 15, lg = lane >> 4;
  const float* hb = hin + (size_t)b * TBUF * 64;

  // ---- stage h -> LDS bf16 [192][64], swizzled ----
#pragma unroll
  for (int it = 0; it < 3; ++it) {
    int row = it * 64 + (tid >> 2);
    int part = tid & 3;                     // 16 channels
    int t = ts + row; if (t < TOFF) t = TOFF;
    const float4* src = (const float4*)(hb + (size_t)(t - TOFF) * 64 + part * 16);
    float4 v0 = src[0], v1 = src[1], v2 = src[2], v3 = src[3];
    short8v p0, p1;
    p0[0]=(short)f2bf(v0.x); p0[1]=(short)f2bf(v0.y); p0[2]=(short)f2bf(v0.z); p0[3]=(short)f2bf(v0.w);
    p0[4]=(short)f2bf(v1.x); p0[5]=(short)f2bf(v1.y); p0[6]=(short)f2bf(v1.z); p0[7]=(short)f2bf(v1.w);
    p1[0]=(short)f2bf(v2.x); p1[1]=(short)f2bf(v2.y); p1[2]=(short)f2bf(v2.z); p1[3]=(short)f2bf(v2.w);
    p1[4]=(short)f2bf(v3.x); p1[5]=(short)f2bf(v3.y); p1[6]=(short)f2bf(v3.z); p1[7]=(short)f2bf(v3.w);
    int base = row * 128 + part * 32;
    *(short8v*)(smem + G_H + ((base)      ^ ((row & 7) << 4))) = p0;
    *(short8v*)(smem + G_H + ((base + 16) ^ ((row & 7) << 4))) = p1;
  }
  // ---- fp32 h -> registers (MFMA C-fragment layout) ----
  f32x4 hreg[3][4];
#pragma unroll
  for (int rf = 0; rf < 3; ++rf)
#pragma unroll
    for (int j = 0; j < 4; ++j)
#pragma unroll
      for (int r = 0; r < 4; ++r) {
        int row = wv * 48 + rf * 16 + lg * 4 + r;
        int t = ts + row; if (t < TOFF) t = TOFF;
        hreg[rf][j][r] = hb[(size_t)(t - TOFF) * 64 + j * 16 + lcol];
      }

  int Rn = R_i0;
#pragma unroll 1
  for (int l = 0; l < 6; ++l) {
    const int layer = i0 + l;
    const int d = 1 << l;
    Rn += d;

    // stage W1 -> G_B, swizzled
    {
      int n = tid >> 1, half = tid & 1;
      const short8v* src = (const short8v*)(W1bf + (size_t)layer * 16384 + n * 128 + half * 64);
#pragma unroll
      for (int c = 0; c < 8; ++c) {
        short8v pk = src[c];
        int byte = (n * 256 + half * 128 + c * 16) ^ ((n & 7) << 4);
        *(short8v*)(smem + G_B + byte) = pk;
      }
    }
    __syncthreads();   // W1 + previous h rewrite visible

    // skip tap at virtual t=L (top block, wave 0; fully wave-private)
    if (top && tid < 64) {
      int rtap = (L_SEQ - d) - ts;          // in [160,191]
      float f = dil_b[layer * 64 + tid], g = gate_b[layer * 64 + tid];
      const float* wd = dil_w  + ((size_t)layer * 64 + tid) * 128;
      const float* wg = gate_w + ((size_t)layer * 64 + tid) * 128;
      for (int ic = 0; ic < 64; ++ic) {
        float hv = bf2f(*(const unsigned short*)(smem + G_H +
                        ((rtap * 128 + ic * 2) ^ ((rtap & 7) << 4))));
        f += wd[ic * 2] * hv;
        g += wg[ic * 2] * hv;
      }
      ztap[tid] = fast_tanh(f) * fast_sigmoid(g);
      // same-wave consume (in-order DS): no barrier needed
      float s = skip_b[layer * 64 + tid];
      const float* wsk = skip_w + ((size_t)layer * 64 + tid) * 64;
      for (int dc = 0; dc < 64; ++dc) s += wsk[dc] * ztap[dc];
      skip_last[b * 64 + tid] += s;
    }

    // Wr fragments (global, L2-hot)
    short8v wr[4][2];
    const unsigned short* wrp = Wrbf + (size_t)layer * 4096;
#pragma unroll
    for (int j2 = 0; j2 < 4; ++j2)
#pragma unroll
      for (int s2 = 0; s2 < 2; ++s2)
        wr[j2][s2] = *(const short8v*)(wrp + (j2 * 16 + lcol) * 64 + s2 * 32 + lg * 8);

#pragma unroll
    for (int rf = 0; rf < 3; ++rf) {
      int arow = wv * 48 + rf * 16 + lcol;
      short8v a[4];
#pragma unroll
      for (int s = 0; s < 4; ++s) {        // s<2: hprev(t-d), s>=2: hcur(t)
        int srcr = arow - ((s < 2) ? d : 0);
        if (srcr < 0) srcr = 0;            // garbage ok; masked
        a[s] = lds_frag(smem, G_H, srcr, (s & 1) * 32 + lg * 8, 128);
      }
      f32x4 cf[8];
#pragma unroll
      for (int j = 0; j < 8; ++j) {
        int n = j * 16 + lcol;
        float bias = (n < 64) ? dil_b[layer * 64 + n] : gate_b[layer * 64 + n - 64];
        cf[j] = (f32x4){bias, bias, bias, bias};
      }
#pragma unroll
      for (int s = 0; s < 4; ++s)
#pragma unroll
        for (int j = 0; j < 8; ++j) {
          short8v bb = lds_frag(smem, G_B, j * 16 + lcol, s * 32 + lg * 8, 256);
          cf[j] = __builtin_amdgcn_mfma_f32_16x16x32_bf16(a[s], bb, cf[j], 0, 0, 0);
        }
      // activation -> wave-private z slot (16 rows)
#pragma unroll
      for (int j = 0; j < 4; ++j)
#pragma unroll
        for (int r = 0; r < 4; ++r) {
          float z = fast_tanh(cf[j][r]) * fast_sigmoid(cf[j + 4][r]);
          int slot = wv * 16 + lg * 4 + r;
          int byte = (slot * 128 + (j * 16 + lcol) * 2) ^ ((slot & 7) << 4);
          *(unsigned short*)(smem + G_Z + byte) = f2bf(z);
        }
      f32x4 c2[4];
#pragma unroll
      for (int j2 = 0; j2 < 4; ++j2) {
        float bias = res_b[layer * 64 + j2 * 16 + lcol];
        c2[j2] = (f32x4){bias, bias, bias, bias};
      }
#pragma unroll
      for (int s2 = 0; s2 < 2; ++s2) {
        short8v a2 = lds_frag(smem, G_Z, wv * 16 + lcol, s2 * 32 + lg * 8, 128);
#pragma unroll
        for (int j2 = 0; j2 < 4; ++j2)
          c2[j2] = __builtin_amdgcn_mfma_f32_16x16x32_bf16(a2, wr[j2][s2], c2[j2], 0, 0, 0);
      }
#pragma unroll
      for (int j2 = 0; j2 < 4; ++j2)
#pragma unroll
        for (int r = 0; r < 4; ++r) {
          int trow = ts + wv * 48 + rf * 16 + lg * 4 + r;
          if (trow >= Rn) hreg[rf][j2][r] += c2[j2][r];
        }
    }
    __syncthreads();   // all reads of h_l done

    // rewrite bf16 h (all own rows; garbage rows never validly read)
#pragma unroll
    for (int rf = 0; rf < 3; ++rf)
#pragma unroll
      for (int j = 0; j < 4; ++j)
#pragma unroll
        for (int r = 0; r < 4; ++r) {
          int row = wv * 48 + rf * 16 + lg * 4 + r;
          int byte = (row * 128 + (j * 16 + lcol) * 2) ^ ((row & 7) << 4);
          *(unsigned short*)(smem + G_H + byte) = f2bf(hreg[rf][j][r]);
        }
    // next iteration's W1-stage barrier makes this visible
  }

  // ---- epilogue: write owned valid rows fp32 ----
#pragma unroll
  for (int rf = 0; rf < 3; ++rf)
#pragma unroll
    for (int j2 = 0; j2 < 4; ++j2)
#pragma unroll
      for (int r = 0; r < 4; ++r) {
        int row = wv * 48 + rf * 16 + lg * 4 + r;
        int t = ts + row;
        if (row >= 64 && t >= Rn)
          hout[((size_t)b * TBUF + t - TOFF) * 64 + j2 * 16 + lcol] = hreg[rf][j2][r];
      }
}

// ---------------------------------------------------------------------------
// single-layer kernel (d >= 64): round-7 proven version
// ---------------------------------------------------------------------------
__global__ __launch_bounds__(512, 4) void layer_kernel(
    const float* __restrict__ hin, float* __restrict__ hout,
    const unsigned short* __restrict__ W1bf, const unsigned short* __restrict__ Wrbf,
    const float* __restrict__ dil_w, const float* __restrict__ gate_w,
    const float* __restrict__ skip_w,
    const float* __restrict__ dil_b, const float* __restrict__ gate_b,
    const float* __restrict__ res_b, const float* __restrict__ skip_b,
    float* __restrict__ skip_last, int layer, int d, int tstart)
{
  extern __shared__ char smem[];
  const int b = blockIdx.y;
  const int tid = threadIdx.x;

  if (blockIdx.x == gridDim.x - 1) {
    float* hp = (float*)smem;
    float* zl = hp + 64;
    if (tid < 64)
      hp[tid] = hin[((size_t)b * TBUF + (L_SEQ - d - TOFF)) * 64 + tid];
    __syncthreads();
    if (tid < 64) {
      int dc = tid;
      float f = dil_b[layer * 64 + dc], gg = gate_b[layer * 64 + dc];
      const float* wd = dil_w  + (size_t)(layer * 64 + dc) * 128;
      const float* wg = gate_w + (size_t)(layer * 64 + dc) * 128;
      for (int ic = 0; ic < 64; ++ic) {
        f  += wd[ic * 2] * hp[ic];
        gg += wg[ic * 2] * hp[ic];
      }
      zl[dc] = fast_tanh(f) * fast_sigmoid(gg);
    }
    __syncthreads();
    if (tid < 64) {
      int co = tid;
      float s = skip_b[layer * 64 + co];
      const float* wsk = skip_w + (size_t)(layer * 64 + co) * 64;
      for (int dc = 0; dc < 64; ++dc) s += wsk[dc] * zl[dc];
      skip_last[b * 64 + co] += s;
    }
    return;
  }

  const int t0 = tstart + blockIdx.x * 128;

  {
    int row = tid >> 2, part = tid & 3;
    int t = t0 + row; if (t >= L_SEQ) t = L_SEQ - 1;
    int tsrc = (part < 2) ? (t - d) : t;
    const float* src = hin + ((size_t)b * TBUF + (tsrc - TOFF)) * 64 + (part & 1) * 32;
    float v[32];
#pragma unroll
    for (int q = 0; q < 8; ++q) {
      float4 f4 = ((const float4*)src)[q];
      v[4*q] = f4.x; v[4*q+1] = f4.y; v[4*q+2] = f4.z; v[4*q+3] = f4.w;
    }
#pragma unroll
    for (int c = 0; c < 4; ++c) {
      short8v pk;
#pragma unroll
      for (int e = 0; e < 8; ++e) pk[e] = (short)f2bf(v[c * 8 + e]);
      int byte = (row * 256 + part * 64 + c * 16) ^ ((row & 7) << 4);
      *(short8v*)(smem + L_A + byte) = pk;
    }
  }
  {
    int n = tid >> 2, q = tid & 3;
    const short8v* src =
        (const short8v*)(W1bf + (size_t)layer * 16384 + n * 128 + q * 32);
#pragma unroll
    for (int c = 0; c < 4; ++c) {
      short8v pk = src[c];
      int byte = (n * 256 + q * 64 + c * 16) ^ ((n & 7) << 4);
      *(short8v*)(smem + L_B + byte) = pk;
    }
  }
  __syncthreads();

  const int lane = tid & 63;
  const int wv   = tid >> 6;
  const int r0   = wv * 16;
  const int lcol = lane & 15;
  const int lg   = lane >> 4;

  short8v a[4];
#pragma unroll
  for (int s = 0; s < 4; ++s)
    a[s] = lds_frag(smem, L_A, r0 + lcol, s * 32 + lg * 8, 256);
  f32x4 cf[8];
#pragma unroll
  for (int j = 0; j < 8; ++j) {
    int n = j * 16 + lcol;
    float bias = (n < 64) ? dil_b[layer * 64 + n] : gate_b[layer * 64 + n - 64];
    cf[j] = (f32x4){bias, bias, bias, bias};
  }
#pragma unroll
  for (int s = 0; s < 4; ++s) {
#pragma unroll
    for (int j = 0; j < 8; ++j) {
      short8v bb = lds_frag(smem, L_B, j * 16 + lcol, s * 32 + lg * 8, 256);
      cf[j] = __builtin_amdgcn_mfma_f32_16x16x32_bf16(a[s], bb, cf[j], 0, 0, 0);
    }
  }

#pragma unroll
  for (int j = 0; j < 4; ++j) {
#pragma unroll
    for (int r = 0; r < 4; ++r) {
      float z = fast_tanh(cf[j][r]) * fast_sigmoid(cf[j + 4][r]);
      int row = r0 + lg * 4 + r;
      int byte = (row * 256 + (j * 16 + lcol) * 2) ^ ((row & 7) << 4);
      *(unsigned short*)(smem + L_A + byte) = f2bf(z);
    }
  }

  short8v wr[4][2];
  const unsigned short* wrp = Wrbf + (size_t)layer * 4096;
#pragma unroll
  for (int j2 = 0; j2 < 4; ++j2)
#pragma unroll
    for (int s2 = 0; s2 < 2; ++s2)
      wr[j2][s2] = *(const short8v*)(wrp + (j2 * 16 + lcol) * 64 + s2 * 32 + lg * 8);

  f32x4 c2[4];
#pragma unroll
  for (int j2 = 0; j2 < 4; ++j2) {
    float bias = res_b[layer * 64 + j2 * 16 + lcol];
    c2[j2] = (f32x4){bias, bias, bias, bias};
  }
#pragma unroll
  for (int s2 = 0; s2 < 2; ++s2) {
    short8v a2 = lds_frag(smem, L_A, r0 + lcol, s2 * 32 + lg * 8, 256);
#pragma unroll
    for (int j2 = 0; j2 < 4; ++j2)
      c2[j2] = __builtin_amdgcn_mfma_f32_16x16x32_bf16(a2, wr[j2][s2], c2[j2], 0, 0, 0);
  }
#pragma unroll
  for (int j2 = 0; j2 < 4; ++j2) {
    int col = j2 * 16 + lcol;
#pragma unroll
    for (int r = 0; r < 4; ++r) {
      int t = t0 + r0 + lg * 4 + r;
      if (t < L_SEQ) {
        size_t idx = ((size_t)b * TBUF + t - TOFF) * 64 + col;
        hout[idx] = hin[idx] + c2[j2][r];
      }
    }
  }
}

// ---------------------------------------------------------------------------
__global__ __launch_bounds__(256) void final_kernel(
    const float* __restrict__ skip_last,
    const float* __restrict__ e1w, const float* __restrict__ e1b,
    const float* __restrict__ mw,  const float* __restrict__ mb,
    const float* __restrict__ lw,  const float* __restrict__ lb,
    float* __restrict__ out)
{
  __shared__ float rm[8][32], rl[8][32];
  int b  = threadIdx.x & 31;
  int eg = threadIdx.x >> 5;
  float y1[64];
  const float4* yp = (const float4*)(skip_last + b * 64);
#pragma unroll
  for (int q = 0; q < 16; ++q) {
    float4 v = yp[q];
    y1[4*q+0] = fmaxf(v.x, 0.f); y1[4*q+1] = fmaxf(v.y, 0.f);
    y1[4*q+2] = fmaxf(v.z, 0.f); y1[4*q+3] = fmaxf(v.w, 0.f);
  }
  float mp = 0.f, lp = 0.f;
  for (int ei = 0; ei < 16; ++ei) {
    int e = eg * 16 + ei;
    const float4* wp = (const float4*)(e1w + e * 64);
    float a0 = e1b[e], a1 = 0.f;
#pragma unroll
    for (int q = 0; q < 16; ++q) {
      float4 w4 = wp[q];
      a0 += w4.x * y1[4*q+0] + w4.z * y1[4*q+2];
      a1 += w4.y * y1[4*q+1] + w4.w * y1[4*q+3];
    }
    float a = fmaxf(a0 + a1, 0.f);
    mp += mw[e] * a;
    lp += lw[e] * a;
  }
  rm[eg][b] = mp; rl[eg][b] = lp;
  __syncthreads();
  if (threadIdx.x < 32) {
    int bb = threadIdx.x;
    float m = mb[0], l = lb[0];
#pragma unroll
    for (int g = 0; g < 8; ++g) { m += rm[g][bb]; l += rl[g][bb]; }
    out[bb]      = m;
    out[32 + bb] = l;
    out[64 + bb] = expf(0.5f * l);
  }
}

// ---------------------------------------------------------------------------
extern "C" void kernel_launch(void* const* d_in, const int* in_sizes, int n_in,
                              void* d_out, int out_size, void* d_ws, size_t ws_size,
                              hipStream_t stream)
{
  const float* x       = (const float*)d_in[0];
  const float* input_w = (const float*)d_in[1];
  const float* input_b = (const float*)d_in[2];
  const float* dil_w   = (const float*)d_in[3];
  const float* dil_b   = (const float*)d_in[4];
  const float* gate_w  = (const float*)d_in[5];
  const float* gate_b  = (const float*)d_in[6];
  const float* skip_w  = (const float*)d_in[7];
  const float* skip_b  = (const float*)d_in[8];
  const float* res_w   = (const float*)d_in[9];
  const float* res_b   = (const float*)d_in[10];
  const float* e1w     = (const float*)d_in[11];
  const float* e1b     = (const float*)d_in[12];
  const float* mw      = (const float*)d_in[13];
  const float* mb      = (const float*)d_in[14];
  const float* lw      = (const float*)d_in[15];
  const float* lb      = (const float*)d_in[16];
  float* out = (float*)d_out;

  float* ws        = (float*)d_ws;
  float* hA        = ws;
  float* hB        = hA + HSZ;
  float* skip_last = hB + HSZ;
  unsigned short* W1bf = (unsigned short*)(skip_last + BATCH * 64);
  unsigned short* Wrbf = W1bf + (size_t)NLAYERS * 128 * 128;

  int dil[NLAYERS];
  int R[NLAYERS + 1];
  for (int blk = 0; blk < 3; ++blk)
    for (int l = 0; l < 10; ++l) dil[blk * 10 + l] = 1 << l;
  R[NLAYERS] = L_SEQ;
  for (int i = NLAYERS - 1; i >= 0; --i) R[i] = R[i + 1] - dil[i];
  // R[0] == 1027

  prep_kernel<<<(NLAYERS * 128 * 128 + 255) / 256, 256, 0, stream>>>(
      dil_w, gate_w, res_w, W1bf, Wrbf, skip_last);

  {
    int nt = L_SEQ - R[0];  // 3069
    dim3 g((nt + 255) / 256, BATCH);
    input_conv_kernel<<<g, 256, 0, stream>>>(x, input_w, input_b, hA);
  }

  float* hin  = hA;
  float* hout = hB;
  for (int g = 0; g < 3; ++g) {
    int i0 = g * 10;
    // fused layers i0..i0+5 (d = 1..32)
    {
      int Rout = R[i0 + 6];
      int nblk = (L_SEQ - Rout + 127) / 128;
      dim3 gd(nblk, BATCH);
      group_kernel<<<gd, 256, 65536, stream>>>(
          hin, hout, W1bf, Wrbf, dil_w, gate_w, skip_w,
          dil_b, gate_b, res_b, skip_b, skip_last, i0, R[i0]);
      float* tmp = hin; hin = hout; hout = tmp;
    }
    // singles i0+6..i0+9 (d = 64..512)
    for (int k = 6; k < 10; ++k) {
      int i = i0 + k;
      int nt = L_SEQ - R[i + 1];
      dim3 gd((nt + 127) / 128 + 1, BATCH);
      layer_kernel<<<gd, 512, 65536, stream>>>(
          hin, hout, W1bf, Wrbf,
          dil_w, gate_w, skip_w,
          dil_b, gate_b, res_b, skip_b,
          skip_last, i, dil[i], R[i + 1]);
      float* tmp = hin; hin = hout; hout = tmp;
    }
  }

  final_kernel<<<1, 256, 0, stream>>>(skip_last, e1w, e1b, mw, mb, lw, lb, out);
}

// Round 9
// 568.129 us; speedup vs baseline: 1.4143x; 1.4143x over previous
//
#include <hip/hip_runtime.h>
#include <hip/hip_bf16.h>
#include <cstddef>

#define L_SEQ   4096
#define BATCH   32
#define TOFF    1024
#define TBUF    3072
#define NLAYERS 30

typedef __attribute__((ext_vector_type(8))) _Float16 half8;
typedef __attribute__((ext_vector_type(4))) float f32x4;

static const size_t HSZ = (size_t)BATCH * TBUF * 64;   // fp16 elements per h buffer

// layer-kernel LDS (65536 B dynamic -> 2 blocks/CU):
//   A:  128 rows x 128k fp16 (hprev|hcur), stride 256B, swizzled   [0, 32768)
//       z (64ch fp16) overlays bytes [0,128) of each wave's own rows after GEMM1
//   W1: 128 n x 128 k fp16, stride 256B, swizzled                  [32768, 65536)
//       delta (64ch fp32/row, 256B stride, swizzled) overlays W1 after GEMM2
#define L_A  0
#define L_B  32768

__device__ inline float fast_sigmoid(float x) {
  x = fminf(fmaxf(x, -30.f), 30.f);
  return __builtin_amdgcn_rcpf(1.f + __expf(-x));
}
__device__ inline float fast_tanh(float x) {
  x = fminf(fmaxf(x, -15.f), 15.f);
  float e = __expf(-2.f * x);
  return (1.f - e) * __builtin_amdgcn_rcpf(1.f + e);
}
__device__ inline half8 lds_frag(const char* smem, int base, int row, int kk,
                                 int rowstride) {
  int byte = base + row * rowstride + kk * 2;
  byte ^= (row & 7) << 4;
  return *(const half8*)(smem + byte);
}

// ---------------------------------------------------------------------------
// prep: fp16-pack W1 = [30][n=128 (f|g)][k=128 (hprev|hcur)], Wr; zero skip
// ---------------------------------------------------------------------------
__global__ __launch_bounds__(256) void prep_kernel(
    const float* __restrict__ dil_w, const float* __restrict__ gate_w,
    const float* __restrict__ res_w,
    _Float16* __restrict__ W1h, _Float16* __restrict__ Wrh,
    float* __restrict__ skip_last)
{
  int idx = blockIdx.x * 256 + threadIdx.x;
  if (idx < NLAYERS * 128 * 128) {
    int l = idx >> 14, r = idx & 16383, n = r >> 7, k = r & 127;
    const float* src = (n < 64) ? dil_w : gate_w;
    int oc = n & 63;
    float v = src[(((size_t)l * 64 + oc) * 64 + (k & 63)) * 2 + (k >> 6)];
    W1h[idx] = (_Float16)v;
  }
  if (idx < NLAYERS * 64 * 64) Wrh[idx] = (_Float16)res_w[idx];
  if (idx < BATCH * 64) skip_last[idx] = 0.f;
}

// ---------------------------------------------------------------------------
// input 1x1 conv: fp32 compute, fp16 h out via LDS bounce (coalesced stores)
// block: 256 threads = 256 rows; LDS 256 rows x 128B, chunk-XOR swizzled
// ---------------------------------------------------------------------------
__global__ __launch_bounds__(256) void input_conv_kernel(
    const float* __restrict__ x, const float* __restrict__ w,
    const float* __restrict__ bias, _Float16* __restrict__ h)
{
  __shared__ char lds[32768];
  int b = blockIdx.y;
  int t0b = 1027 + blockIdx.x * 256;
  int t = t0b + threadIdx.x;
  if (t < L_SEQ) {
    const float* xp = x + ((size_t)b * L_SEQ + t) * 32;
    float xin[32];
#pragma unroll
    for (int j = 0; j < 8; ++j) {
      float4 v = ((const float4*)xp)[j];
      xin[4*j+0] = v.x; xin[4*j+1] = v.y; xin[4*j+2] = v.z; xin[4*j+3] = v.w;
    }
#pragma unroll
    for (int q = 0; q < 8; ++q) {           // 8 chunks of 8 channels
      half8 pk;
#pragma unroll 2
      for (int o = 0; o < 8; ++o) {
        int oc = q * 8 + o;
        float a0 = bias[oc], a1 = 0.f;
#pragma unroll
        for (int k = 0; k < 32; k += 2) {
          a0 += w[oc * 32 + k]     * xin[k];
          a1 += w[oc * 32 + k + 1] * xin[k + 1];
        }
        pk[o] = (_Float16)(a0 + a1);
      }
      int byte = threadIdx.x * 128 + ((q ^ (threadIdx.x & 7)) * 16);
      *(half8*)(lds + byte) = pk;
    }
  }
  __syncthreads();
  _Float16* hb = h + (size_t)b * TBUF * 64;
#pragma unroll
  for (int p = 0; p < 8; ++p) {
    int B = (p * 256 + threadIdx.x) * 16;
    int row = B >> 7;
    int q = (B >> 4) & 7;
    int tg = t0b + row;
    if (tg < L_SEQ) {
      half8 v = *(const half8*)(lds + row * 128 + ((q ^ (row & 7)) * 16));
      *(half8*)(hb + (size_t)(tg - TOFF) * 64 + q * 8) = v;
    }
  }
}

// ---------------------------------------------------------------------------
// fused MFMA layer (fp16): block = 128 positions x 1 batch, 8 waves.
// tail block: skip tap at virtual t = L (VALU)
// ---------------------------------------------------------------------------
__global__ __launch_bounds__(512, 4) void layer_kernel(
    const _Float16* __restrict__ hin, _Float16* __restrict__ hout,
    const _Float16* __restrict__ W1h, const _Float16* __restrict__ Wrh,
    const float* __restrict__ dil_w, const float* __restrict__ gate_w,
    const float* __restrict__ skip_w,
    const float* __restrict__ dil_b, const float* __restrict__ gate_b,
    const float* __restrict__ res_b, const float* __restrict__ skip_b,
    float* __restrict__ skip_last, int layer, int d, int tstart)
{
  extern __shared__ char smem[];
  const int b = blockIdx.y;
  const int tid = threadIdx.x;

  if (blockIdx.x == gridDim.x - 1) {
    // ---- skip tail at t=L: z uses only tap0 at h[L-d] ----
    float* hp = (float*)smem;
    float* zl = hp + 64;
    if (tid < 64)
      hp[tid] = (float)hin[((size_t)b * TBUF + (L_SEQ - d - TOFF)) * 64 + tid];
    __syncthreads();
    if (tid < 64) {
      int dc = tid;
      float f = dil_b[layer * 64 + dc], gg = gate_b[layer * 64 + dc];
      const float* wd = dil_w  + (size_t)(layer * 64 + dc) * 128;
      const float* wg = gate_w + (size_t)(layer * 64 + dc) * 128;
      for (int ic = 0; ic < 64; ++ic) {
        f  += wd[ic * 2] * hp[ic];
        gg += wg[ic * 2] * hp[ic];
      }
      zl[dc] = fast_tanh(f) * fast_sigmoid(gg);
    }
    __syncthreads();
    if (tid < 64) {
      int co = tid;
      float s = skip_b[layer * 64 + co];
      const float* wsk = skip_w + (size_t)(layer * 64 + co) * 64;
      for (int dc = 0; dc < 64; ++dc) s += wsk[dc] * zl[dc];
      skip_last[b * 64 + co] += s;   // race-free: launches serialize layers
    }
    return;
  }

  const int t0 = tstart + blockIdx.x * 128;
  const _Float16* hb = hin + (size_t)b * TBUF * 64;

  // ---- stage A: 128 rows x (hprev 64 | hcur 64) fp16, straight copy ----
  {
    int row = tid >> 2, part = tid & 3;
    int t = t0 + row; if (t >= L_SEQ) t = L_SEQ - 1;   // clamp; masked at out
    int tsrc = (part < 2) ? (t - d) : t;
    const half8* src = (const half8*)(hb + (size_t)(tsrc - TOFF) * 64 + (part & 1) * 32);
#pragma unroll
    for (int c = 0; c < 4; ++c) {
      half8 pk = src[c];
      int byte = (row * 256 + part * 64 + c * 16) ^ ((row & 7) << 4);
      *(half8*)(smem + L_A + byte) = pk;
    }
  }
  // ---- stage W1: 128 n x 128 k fp16 ----
  {
    int n = tid >> 2, q = tid & 3;
    const half8* src = (const half8*)(W1h + (size_t)layer * 16384 + n * 128 + q * 32);
#pragma unroll
    for (int c = 0; c < 4; ++c) {
      half8 pk = src[c];
      int byte = (n * 256 + q * 64 + c * 16) ^ ((n & 7) << 4);
      *(half8*)(smem + L_B + byte) = pk;
    }
  }
  __syncthreads();   // barrier 1

  const int lane = tid & 63;
  const int wv   = tid >> 6;
  const int r0   = wv * 16;
  const int lcol = lane & 15;
  const int lg   = lane >> 4;

  // ---- GEMM1 ----
  half8 a[4];
#pragma unroll
  for (int s = 0; s < 4; ++s)
    a[s] = lds_frag(smem, L_A, r0 + lcol, s * 32 + lg * 8, 256);
  f32x4 cf[8];
#pragma unroll
  for (int j = 0; j < 8; ++j) {
    int n = j * 16 + lcol;
    float bias = (n < 64) ? dil_b[layer * 64 + n] : gate_b[layer * 64 + n - 64];
    cf[j] = (f32x4){bias, bias, bias, bias};
  }
#pragma unroll
  for (int s = 0; s < 4; ++s) {
#pragma unroll
    for (int j = 0; j < 8; ++j) {
      half8 bb = lds_frag(smem, L_B, j * 16 + lcol, s * 32 + lg * 8, 256);
      cf[j] = __builtin_amdgcn_mfma_f32_16x16x32_f16(a[s], bb, cf[j], 0, 0, 0);
    }
  }

  // ---- activation -> z overlays wave's own A rows (bytes [0,128)) ----
#pragma unroll
  for (int j = 0; j < 4; ++j) {
#pragma unroll
    for (int r = 0; r < 4; ++r) {
      float z = fast_tanh(cf[j][r]) * fast_sigmoid(cf[j + 4][r]);
      int row = r0 + lg * 4 + r;            // C layout: row=(lane>>4)*4+reg
      int byte = (row * 256 + (j * 16 + lcol) * 2) ^ ((row & 7) << 4);
      *(_Float16*)(smem + L_A + byte) = (_Float16)z;
    }
  }

  // ---- Wr fragments in registers ----
  half8 wr[4][2];
  const _Float16* wrp = Wrh + (size_t)layer * 4096;
#pragma unroll
  for (int j2 = 0; j2 < 4; ++j2)
#pragma unroll
    for (int s2 = 0; s2 < 2; ++s2)
      wr[j2][s2] = *(const half8*)(wrp + (j2 * 16 + lcol) * 64 + s2 * 32 + lg * 8);

  // ---- GEMM2 ----
  f32x4 c2[4];
#pragma unroll
  for (int j2 = 0; j2 < 4; ++j2) {
    float bias = res_b[layer * 64 + j2 * 16 + lcol];
    c2[j2] = (f32x4){bias, bias, bias, bias};
  }
#pragma unroll
  for (int s2 = 0; s2 < 2; ++s2) {
    half8 a2 = lds_frag(smem, L_A, r0 + lcol, s2 * 32 + lg * 8, 256);
#pragma unroll
    for (int j2 = 0; j2 < 4; ++j2)
      c2[j2] = __builtin_amdgcn_mfma_f32_16x16x32_f16(a2, wr[j2][s2], c2[j2], 0, 0, 0);
  }

  __syncthreads();   // barrier 2: all W1 reads done; W1 region becomes delta
  // ---- delta -> LDS (fp32 [128 rows][64 ch], 256B stride, swizzled) ----
#pragma unroll
  for (int j2 = 0; j2 < 4; ++j2) {
#pragma unroll
    for (int r = 0; r < 4; ++r) {
      int row = r0 + lg * 4 + r;
      int byte = (row * 256 + (j2 * 16 + lcol) * 4) ^ ((row & 7) << 4);
      *(float*)(smem + L_B + byte) = c2[j2][r];
    }
  }
  __syncthreads();   // barrier 3

  // ---- cooperative epilogue: hout = hcur(LDS) + delta(LDS), coalesced ----
  {
    int row = tid >> 2, part = tid & 3;
    int t = t0 + row;
    if (t < L_SEQ) {
      float dl[16];
#pragma unroll
      for (int g = 0; g < 4; ++g) {
        int byte = (row * 256 + part * 64 + g * 16) ^ ((row & 7) << 4);
        float4 v = *(const float4*)(smem + L_B + byte);
        dl[4*g+0] = v.x; dl[4*g+1] = v.y; dl[4*g+2] = v.z; dl[4*g+3] = v.w;
      }
      half8 hc0 = *(const half8*)(smem + L_A +
                    ((row * 256 + 128 + part * 32) ^ ((row & 7) << 4)));
      half8 hc1 = *(const half8*)(smem + L_A +
                    ((row * 256 + 128 + part * 32 + 16) ^ ((row & 7) << 4)));
      half8 o0, o1;
#pragma unroll
      for (int e = 0; e < 8; ++e) {
        o0[e] = (_Float16)((float)hc0[e] + dl[e]);
        o1[e] = (_Float16)((float)hc1[e] + dl[8 + e]);
      }
      _Float16* dst = hout + ((size_t)b * TBUF + t - TOFF) * 64 + part * 16;
      *(half8*)dst = o0;
      *(half8*)(dst + 8) = o1;
    }
  }
}

// ---------------------------------------------------------------------------
// final head: relu -> end1 (64->128) -> relu -> mean/lv -> vol
// ---------------------------------------------------------------------------
__global__ __launch_bounds__(256) void final_kernel(
    const float* __restrict__ skip_last,
    const float* __restrict__ e1w, const float* __restrict__ e1b,
    const float* __restrict__ mw,  const float* __restrict__ mb,
    const float* __restrict__ lw,  const float* __restrict__ lb,
    float* __restrict__ out)
{
  __shared__ float rm[8][32], rl[8][32];
  int b  = threadIdx.x & 31;
  int eg = threadIdx.x >> 5;
  float y1[64];
  const float4* yp = (const float4*)(skip_last + b * 64);
#pragma unroll
  for (int q = 0; q < 16; ++q) {
    float4 v = yp[q];
    y1[4*q+0] = fmaxf(v.x, 0.f); y1[4*q+1] = fmaxf(v.y, 0.f);
    y1[4*q+2] = fmaxf(v.z, 0.f); y1[4*q+3] = fmaxf(v.w, 0.f);
  }
  float mp = 0.f, lp = 0.f;
  for (int ei = 0; ei < 16; ++ei) {
    int e = eg * 16 + ei;
    const float4* wp = (const float4*)(e1w + e * 64);
    float a0 = e1b[e], a1 = 0.f;
#pragma unroll
    for (int q = 0; q < 16; ++q) {
      float4 w4 = wp[q];
      a0 += w4.x * y1[4*q+0] + w4.z * y1[4*q+2];
      a1 += w4.y * y1[4*q+1] + w4.w * y1[4*q+3];
    }
    float a = fmaxf(a0 + a1, 0.f);
    mp += mw[e] * a;
    lp += lw[e] * a;
  }
  rm[eg][b] = mp; rl[eg][b] = lp;
  __syncthreads();
  if (threadIdx.x < 32) {
    int bb = threadIdx.x;
    float m = mb[0], l = lb[0];
#pragma unroll
    for (int g = 0; g < 8; ++g) { m += rm[g][bb]; l += rl[g][bb]; }
    out[bb]      = m;
    out[32 + bb] = l;
    out[64 + bb] = expf(0.5f * l);
  }
}

// ---------------------------------------------------------------------------
extern "C" void kernel_launch(void* const* d_in, const int* in_sizes, int n_in,
                              void* d_out, int out_size, void* d_ws, size_t ws_size,
                              hipStream_t stream)
{
  const float* x       = (const float*)d_in[0];
  const float* input_w = (const float*)d_in[1];
  const float* input_b = (const float*)d_in[2];
  const float* dil_w   = (const float*)d_in[3];
  const float* dil_b   = (const float*)d_in[4];
  const float* gate_w  = (const float*)d_in[5];
  const float* gate_b  = (const float*)d_in[6];
  const float* skip_w  = (const float*)d_in[7];
  const float* skip_b  = (const float*)d_in[8];
  const float* res_w   = (const float*)d_in[9];
  const float* res_b   = (const float*)d_in[10];
  const float* e1w     = (const float*)d_in[11];
  const float* e1b     = (const float*)d_in[12];
  const float* mw      = (const float*)d_in[13];
  const float* mb      = (const float*)d_in[14];
  const float* lw      = (const float*)d_in[15];
  const float* lb      = (const float*)d_in[16];
  float* out = (float*)d_out;

  _Float16* hA        = (_Float16*)d_ws;
  _Float16* hB        = hA + HSZ;
  float*    skip_last = (float*)(hB + HSZ);
  _Float16* W1h       = (_Float16*)(skip_last + BATCH * 64);
  _Float16* Wrh       = W1h + (size_t)NLAYERS * 128 * 128;

  int dil[NLAYERS];
  int R[NLAYERS + 1];
  for (int blk = 0; blk < 3; ++blk)
    for (int l = 0; l < 10; ++l) dil[blk * 10 + l] = 1 << l;
  R[NLAYERS] = L_SEQ;
  for (int i = NLAYERS - 1; i >= 0; --i) R[i] = R[i + 1] - dil[i];
  // R[0] == 1027

  prep_kernel<<<(NLAYERS * 128 * 128 + 255) / 256, 256, 0, stream>>>(
      dil_w, gate_w, res_w, W1h, Wrh, skip_last);

  {
    int nt = L_SEQ - R[0];  // 3069
    dim3 g((nt + 255) / 256, BATCH);
    input_conv_kernel<<<g, 256, 0, stream>>>(x, input_w, input_b, hA);
  }

  _Float16* hin  = hA;
  _Float16* hout = hB;
  for (int i = 0; i < NLAYERS; ++i) {
    int nt = L_SEQ - R[i + 1];            // normal positions (0 for last layer)
    dim3 g((nt + 127) / 128 + 1, BATCH);  // +1 tail block for skip @ t=L
    layer_kernel<<<g, 512, 65536, stream>>>(
        hin, hout, W1h, Wrh,
        dil_w, gate_w, skip_w,
        dil_b, gate_b, res_b, skip_b,
        skip_last, i, dil[i], R[i + 1]);
    _Float16* tmp = hin; hin = hout; hout = tmp;
  }

  final_kernel<<<1, 256, 0, stream>>>(skip_last, e1w, e1b, mw, mb, lw, lb, out);
}